// Round 12
// baseline (483.063 us; speedup 1.0000x reference)
//
#include <hip/hip_runtime.h>

// ---- problem constants (b=16, f=8, p=196, dim=768, H=12) ----
#define NB   16
#define NH   12
#define NSEQ 1569
#define DIMM 768
#define QS   (3 * DIMM)     // qkv row stride 2304
#define PDIM 196
#define FF   8
#define DH   64
#define MROWS (NB * NSEQ)   // 25104

typedef short short8 __attribute__((ext_vector_type(8)));
typedef float float4v __attribute__((ext_vector_type(4)));

__device__ __forceinline__ float bf2f(ushort u) {
    union { uint i; float f; } w; w.i = ((uint)u) << 16; return w.f;
}
__device__ __forceinline__ ushort f2bf(float f) {
    union { float f; uint i; } w; w.f = f;
    uint x = w.i;
    return (ushort)((x + 0x7FFFu + ((x >> 16) & 1u)) >> 16);
}
__device__ __forceinline__ float in_ld(const void* p, size_t idx, int f32) {
    return f32 ? ((const float*)p)[idx] : bf2f(((const ushort*)p)[idx]);
}

// async global->LDS, 16B per lane; LDS dest = wave-uniform base + lane*16
__device__ __forceinline__ void gload_lds16(const ushort* g, ushort* l) {
    __builtin_amdgcn_global_load_lds(
        (const __attribute__((address_space(1))) unsigned int*)g,
        (__attribute__((address_space(3))) unsigned int*)l,
        16, 0, 0);
}

// bijective XCD-aware block swizzle (m204)
__device__ __forceinline__ int xcd_swizzle(int orig, int nwg) {
    int qd = nwg >> 3, rd = nwg & 7;
    int xcd = orig & 7, loc = orig >> 3;
    return (xcd < rd ? xcd * (qd + 1) : rd * (qd + 1) + (xcd - rd) * qd) + loc;
}

// ======================= prep: self-detect + conv x->bf16 + transposes =======================
#define CVB 1024   // conv blocks
#define TQB 1728   // Wqkv transpose blocks (72 x 24)
#define TPB 576    // Wproj transpose blocks (24 x 24)

__device__ __forceinline__ void transpose_body(
    const void* __restrict__ W, ushort* __restrict__ WT,
    int K, int N, int b, int fl, ushort (*t)[33], int tid)
{
    const int nbx = N / 32;
    const int bx = b % nbx, by = b / nbx;
    const int tx = tid & 31, ty = tid >> 5;   // 32x8
#pragma unroll
    for (int i = 0; i < 4; ++i) {
        int r = by * 32 + ty + i * 8;
        t[ty + i * 8][tx] = f2bf(in_ld(W, (size_t)r * N + bx * 32 + tx, fl));
    }
    __syncthreads();
#pragma unroll
    for (int i = 0; i < 4; ++i) {
        int r = bx * 32 + ty + i * 8;
        WT[(size_t)r * K + by * 32 + tx] = t[tx][ty + i * 8];
    }
}

__global__ __launch_bounds__(256)
void prep(const void* __restrict__ x, ushort* __restrict__ xb,
          const void* __restrict__ Wqkv, ushort* __restrict__ wqkvT,
          const void* __restrict__ Wproj, ushort* __restrict__ wprojT,
          int* __restrict__ flags, int* __restrict__ cnt)
{
    __shared__ ushort t[32][33];
    __shared__ int anyBig;
    const int b = blockIdx.x, tid = threadIdx.x;

    // block-local dtype detect from Wqkv (fp32-as-ushort has random exponents)
    if (tid == 0) anyBig = 0;
    __syncthreads();
    {
        const ushort* w = (const ushort*)Wqkv;
        for (int i = tid; i < 2048; i += 256) {
            int e = (w[i] >> 7) & 0xFF;
            if (e >= 134) anyBig = 1;
        }
    }
    __syncthreads();
    const int fl = anyBig;

    if (b == 0) {
        if (tid == 0) flags[0] = fl;
        for (int i = tid; i < NB * NH; i += 256) cnt[i] = 0;   // cls finisher counters
    }

    if (b < CVB) {
        const size_t n = (size_t)MROWS * DIMM;
        const size_t stride = (size_t)CVB * 256;
        size_t i = (size_t)b * 256 + tid;
        if (fl) {
            for (size_t j = i; j < n / 4; j += stride) {
                float4 f = ((const float4*)x)[j];
                union { uint2 u; ushort s[4]; } w;
                w.s[0] = f2bf(f.x); w.s[1] = f2bf(f.y);
                w.s[2] = f2bf(f.z); w.s[3] = f2bf(f.w);
                ((uint2*)xb)[j] = w.u;
            }
        } else {
            for (size_t j = i; j < n / 8; j += stride)
                ((uint4*)xb)[j] = ((const uint4*)x)[j];
        }
    } else if (b < CVB + TQB) {
        transpose_body(Wqkv, wqkvT, DIMM, 3 * DIMM, b - CVB, fl, t, tid);
    } else {
        transpose_body(Wproj, wprojT, DIMM, DIMM, b - CVB - TQB, fl, t, tid);
    }
}

// ======================= 256x256 8-phase MFMA GEMM (R8 schedule) =======================
// A bf16 [M][K], Bt bf16 [N][K]. 8 waves (2Mx4N), per-wave out 128x64.
// LDS 128 KB: A/B x dbuf x 2 halves of [128][64].
// Schedule (4 phases per K-tile T, counted vmcnt, never 0):
//   B-frags of tile T are ds-read ONLY in T.p1 (held in regs), so B slot
//   frees after p1. Stage: A(T+1) at T.p1/p2; B(T+2) at T.p2/p3 into the
//   freed B half. At T.p4 boundary: outstanding = B(T+2) only = 4 gloads
//   -> s_waitcnt vmcnt(4); A(T+1)/B(T+1) (older) are forced complete.
// T2 swizzle (rule #21 both-sides): linear gload_lds dest; SOURCE slot
//   pre-XORed (sslot = (tid&7)^(row&7)); ds_read XORs slot with (row&7).
#define BM2 256
#define BN2 256
#define BK  64

#define STG_A(s, h, k0) do { \
    gload_lds16(aS[2*(h)]   + (k0), &As[s][h][(size_t)tid * 8]);        \
    gload_lds16(aS[2*(h)+1] + (k0), &As[s][h][(size_t)(tid + 512) * 8]); } while (0)
#define STG_B(s, h, k0) do { \
    gload_lds16(bS[2*(h)]   + (k0), &Bs[s][h][(size_t)tid * 8]);        \
    gload_lds16(bS[2*(h)+1] + (k0), &Bs[s][h][(size_t)(tid + 512) * 8]); } while (0)

#define PH_A_READS(m0) do { \
    af[0][0] = *(const short8*)(Acur + (m0) * 1024 + l16 * 64 + xs0);      \
    af[0][1] = *(const short8*)(Acur + (m0) * 1024 + l16 * 64 + xs1);      \
    af[1][0] = *(const short8*)(Acur + ((m0)+1) * 1024 + l16 * 64 + xs0);  \
    af[1][1] = *(const short8*)(Acur + ((m0)+1) * 1024 + l16 * 64 + xs1); } while (0)

#define PH_MFMA(m0) do { \
    asm volatile("" ::: "memory"); \
    __builtin_amdgcn_s_barrier(); \
    __builtin_amdgcn_s_setprio(1); \
    _Pragma("unroll") \
    for (int kk = 0; kk < 2; ++kk) \
        _Pragma("unroll") \
        for (int mi = 0; mi < 2; ++mi) \
            _Pragma("unroll") \
            for (int n = 0; n < 4; ++n) \
                acc[(m0)+mi][n] = __builtin_amdgcn_mfma_f32_16x16x32_bf16( \
                    af[mi][kk], bf[n][kk], acc[(m0)+mi][n], 0, 0, 0); \
    __builtin_amdgcn_s_setprio(0); } while (0)

#define PH_END() do { \
    asm volatile("" ::: "memory"); \
    __builtin_amdgcn_s_barrier(); } while (0)

#define PH_END_VM() do { \
    asm volatile("s_waitcnt vmcnt(4)" ::: "memory"); \
    __builtin_amdgcn_s_barrier(); } while (0)

template<int MODE>
__global__ __launch_bounds__(512, 2)
void gemm256(const ushort* __restrict__ A, const ushort* __restrict__ Bt,
             const void* __restrict__ bias,
             ushort* __restrict__ ob, float* __restrict__ of,
             int M, int N, int K, const int* __restrict__ flags)
{
    __shared__ __align__(16) ushort As[2][2][128 * 64];   // 64 KB
    __shared__ __align__(16) ushort Bs[2][2][128 * 64];   // 64 KB

    const int nbn = N / BN2;
    const int wg  = xcd_swizzle(blockIdx.x, gridDim.x);
    const int mb  = wg / nbn, nb = wg % nbn;
    const int Mb  = mb * BM2, Nbs = nb * BN2;

    const int tid = threadIdx.x, lane = tid & 63, wid = tid >> 6;
    const int wm  = wid >> 2;            // 0..1 : row half
    const int wn  = wid & 3;             // 0..3 : 64-col strip
    const int q4  = lane >> 4, l16 = lane & 15;

    // staging source (inverse-swizzled 16B slot)
    const int r0    = tid >> 3;                       // 0..63
    const int sslot = (tid & 7) ^ (r0 & 7);
    const ushort* aS[4]; const ushort* bS[4];
#pragma unroll
    for (int jj = 0; jj < 4; ++jj) {
        int ar = Mb + jj * 64 + r0; if (ar >= M) ar = M - 1;
        aS[jj] = A + (size_t)ar * K + sslot * 8;
        int br = Nbs + jj * 64 + r0;                  // N multiple of 256
        bS[jj] = Bt + (size_t)br * K + sslot * 8;
    }

    // ds_read swizzled slot offsets (row&7 == l16&7 since rows step by 16)
    const int xs0 = ((0 + q4) ^ (l16 & 7)) * 8;       // kk=0
    const int xs1 = ((4 + q4) ^ (l16 & 7)) * 8;       // kk=1

    float4v acc[8][4];
#pragma unroll
    for (int m = 0; m < 8; ++m)
#pragma unroll
        for (int n = 0; n < 4; ++n) acc[m][n] = (float4v){0.f, 0.f, 0.f, 0.f};

    const int NT = K / BK;   // 12

    // ---- prologue: A(0), B(0), B(1) ----
    STG_A(0, 0, 0); STG_A(0, 1, 0);
    STG_B(0, 0, 0); STG_B(0, 1, 0);
    STG_B(1, 0, BK); STG_B(1, 1, BK);
    asm volatile("s_waitcnt vmcnt(4)" ::: "memory");   // A(0),B(0) landed
    __builtin_amdgcn_s_barrier();

    for (int T = 0; T < NT; ++T) {
        const int cur = T & 1, nxt = cur ^ 1;
        const int k1 = (T + 1) * BK, k2 = (T + 2) * BK;
        const ushort* Acur = &As[cur][wm][0];
        short8 bf[4][2];
        short8 af[2][2];

        // ---- phase 1: read all B-frags + A rows 0-31; stage A0(T+1) ----
#pragma unroll
        for (int n = 0; n < 4; ++n) {
            int c = wn * 64 + n * 16 + l16;
            const ushort* Bh = &Bs[cur][c >> 7][(c & 127) * 64];
            bf[n][0] = *(const short8*)(Bh + xs0);
            bf[n][1] = *(const short8*)(Bh + xs1);
        }
        PH_A_READS(0);
        if (T + 1 < NT) STG_A(nxt, 0, k1);
        PH_MFMA(0);
        PH_END();

        // ---- phase 2: A rows 32-63; stage A1(T+1), B0(T+2) ----
        PH_A_READS(2);
        if (T + 1 < NT) STG_A(nxt, 1, k1);
        if (T + 2 < NT) STG_B(cur, 0, k2);
        PH_MFMA(2);
        PH_END();

        // ---- phase 3: A rows 64-95; stage B1(T+2) ----
        PH_A_READS(4);
        if (T + 2 < NT) STG_B(cur, 1, k2);
        PH_MFMA(4);
        PH_END();

        // ---- phase 4: A rows 96-127; boundary vmcnt(4) ----
        PH_A_READS(6);
        PH_MFMA(6);
        PH_END_VM();
    }

    // ---- epilogue ----
    const int fl = (MODE == 1) ? flags[0] : 0;
#pragma unroll
    for (int m = 0; m < 8; ++m)
#pragma unroll
        for (int n = 0; n < 4; ++n) {
            int col = Nbs + wn * 64 + n * 16 + l16;
            int rb  = Mb + wm * 128 + m * 16 + q4 * 4;
            if (MODE == 0) {
                float sc = (col < DIMM) ? 0.125f : 1.0f;
#pragma unroll
                for (int i = 0; i < 4; ++i) {
                    int row = rb + i;
                    if (row < M)
                        ob[(size_t)row * QS + col] = f2bf(acc[m][n][i] * sc);
                }
            } else {
                float bv = in_ld(bias, col, fl);
#pragma unroll
                for (int i = 0; i < 4; ++i) {
                    int row = rb + i;
                    if (row < M)
                        of[(size_t)row * N + col] = acc[m][n][i] + bv;
                }
            }
        }
}

// ======================= fused attention =======================
// blocks [0,1536): spatial (b,h,f); blocks [1536,3072): cls split-K chunk
// (b,h,ch) — concurrent with spatial. Last-finishing chunk block per bh
// does the combine (device-scope fence + atomic ticket, G16-safe).
#define CCH 8
#define CLK 197
#define SQT   13
#define SKEY  208
#define KSTR  72
#define VSTR  232
#define PSC   72

__global__ __launch_bounds__(512, 4)
void attn_all(const ushort* __restrict__ qkv, const void* __restrict__ mask,
              ushort* __restrict__ ab, float* __restrict__ part,
              int* __restrict__ cnt, const int* __restrict__ flags)
{
    const int fl  = flags[0];
    const int tid = threadIdx.x, lane = tid & 63, wid = tid >> 6;

    __shared__ __align__(16) ushort Ks[SKEY][KSTR];   // 29.9 KB
    __shared__ __align__(16) ushort Vt[DH][VSTR];     // 29.0 KB
    __shared__ __align__(16) ushort Ps[8][16][PSC];   // 18.0 KB
    __shared__ float bias_s[SKEY];                    // ~77 KB total
    __shared__ int ticket;

    if (blockIdx.x >= 1536) {
        // =================== CLS split-K chunk (512 threads) ===================
        const int bid = blockIdx.x - 1536;
        const int bh  = bid >> 3, ch = bid & 7;
        const int bi  = bh / NH, hi = bh - bi * NH;
        const int j0  = ch * CLK;
        const int j1  = (j0 + CLK < NSEQ) ? j0 + CLK : NSEQ;
        const int n   = j1 - j0;

        float* pool   = (float*)&Ks[0][0];
        float* qs     = pool;          // 64
        float* simbuf = pool + 64;     // 197
        float* redm   = pool + 264;    // 8
        float* redl   = pool + 272;    // 8
        float* osum   = pool + 288;    // 8*64

        const size_t rowb = (size_t)bi * NSEQ;
        if (tid < DH) qs[tid] = bf2f(qkv[rowb * QS + hi * DH + tid]);
        __syncthreads();

        for (int j = tid; j < n; j += 512) {
            int jj = j0 + j;
            const ushort* kr = qkv + (rowb + jj) * QS + DIMM + hi * DH;
            float s = 0.f;
#pragma unroll
            for (int c = 0; c < 8; ++c) {
                union { uint4 u; ushort e[8]; } w;
                w.u = *(const uint4*)(kr + c * 8);
#pragma unroll
                for (int i = 0; i < 8; ++i) s += qs[c * 8 + i] * bf2f(w.e[i]);
            }
            int sp = (jj == 0) ? 0 : 1 + ((jj - 1) % PDIM);
            s += (1.0f - in_ld(mask, bi * (1 + PDIM) + sp, fl)) * -10000.0f;
            simbuf[j] = s;
        }
        __syncthreads();

        float m = -3e38f;
        for (int j = tid; j < n; j += 512) m = fmaxf(m, simbuf[j]);
#pragma unroll
        for (int o = 32; o > 0; o >>= 1) m = fmaxf(m, __shfl_xor(m, o));
        if (lane == 0) redm[wid] = m;
        __syncthreads();
        m = redm[0];
#pragma unroll
        for (int c = 1; c < 8; ++c) m = fmaxf(m, redm[c]);

        float ls = 0.f;
        for (int j = tid; j < n; j += 512) {
            float p = __expf(simbuf[j] - m);
            simbuf[j] = p;
            ls += p;
        }
#pragma unroll
        for (int o = 32; o > 0; o >>= 1) ls += __shfl_xor(ls, o);
        if (lane == 0) redl[wid] = ls;
        __syncthreads();

        int g = wid, di = tid & 63;
        float acc = 0.f;
        for (int j = g; j < n; j += 8)
            acc += simbuf[j] * bf2f(qkv[(rowb + j0 + j) * QS + 2 * DIMM + hi * DH + di]);
        osum[g * DH + di] = acc;
        __syncthreads();

        float* dst = part + (size_t)bid * (DH + 2);
        if (tid < DH) {
            float o = 0.f;
#pragma unroll
            for (int c = 0; c < 8; ++c) o += osum[c * DH + tid];
            dst[2 + tid] = o;
        }
        if (tid == 0) {
            float l = 0.f;
#pragma unroll
            for (int c = 0; c < 8; ++c) l += redl[c];
            dst[0] = m; dst[1] = l;
        }

        // ---- finisher: last chunk for this bh combines ----
        __syncthreads();                       // partials written by all threads
        if (tid == 0) {
            __threadfence();                   // release partials (device scope)
            ticket = atomicAdd(&cnt[bh], 1);
        }
        __syncthreads();
        if (ticket == CCH - 1 && tid < DH) {
            __threadfence();                   // acquire other chunks' partials
            const float* p = part + (size_t)bh * CCH * (DH + 2);
            float mm = -3e38f;
#pragma unroll
            for (int c = 0; c < CCH; ++c) mm = fmaxf(mm, p[c * (DH + 2)]);
            float ll = 0.f, oo = 0.f;
#pragma unroll
            for (int c = 0; c < CCH; ++c) {
                float w = __expf(p[c * (DH + 2)] - mm);
                ll += p[c * (DH + 2) + 1] * w;
                oo += p[c * (DH + 2) + 2 + tid] * w;
            }
            ab[((size_t)bi * NSEQ) * DIMM + hi * DH + tid] = f2bf(oo / ll);
        }
        return;
    }

    // =================== spatial MFMA ===================
    const int bhf = blockIdx.x;
    const int bh  = bhf >> 3, fi = bhf & 7;
    const int bi  = bh / NH, hi = bh - bi * NH;
    const int q4  = lane >> 4, l16 = lane & 15;

    const size_t rowb = (size_t)bi * NSEQ;

    for (int j = tid; j < SKEY; j += 512)
        bias_s[j] = (j < 197) ? (1.0f - in_ld(mask, bi * 197 + j, fl)) * -10000.0f
                              : -3.0e38f;

    for (int c = tid; c < SKEY * (DH / 8); c += 512) {
        int j = c >> 3, off = (c & 7) * 8;
        int jj = j > 196 ? 196 : j;
        int row = (jj == 0) ? 0 : (fi * PDIM + jj);
        *(uint4*)&Ks[j][off] =
            *(const uint4*)(qkv + (rowb + row) * QS + DIMM + hi * DH + off);
    }
    for (int c = tid; c < 224 * (DH / 8); c += 512) {
        int j = c >> 3, off = (c & 7) * 8;
        int jj = j > 196 ? 196 : j;
        int row = (jj == 0) ? 0 : (fi * PDIM + jj);
        union { uint4 u; ushort e[8]; } w;
        w.u = *(const uint4*)(qkv + (rowb + row) * QS + 2 * DIMM + hi * DH + off);
#pragma unroll
        for (int i = 0; i < 8; ++i) Vt[off + i][j] = w.e[i];
    }
    __syncthreads();

    for (int qt = wid; qt < SQT; qt += 8) {
        int qi = qt * 16 + l16;
        int qc = qi > 195 ? 195 : qi;
        const ushort* qp = qkv + (rowb + 1 + fi * PDIM + qc) * QS + hi * DH;
        short8 a0 = *(const short8*)(qp + q4 * 8);
        short8 a1 = *(const short8*)(qp + 32 + q4 * 8);

        float4v s[13];
#pragma unroll
        for (int t = 0; t < 13; ++t) {
            float4v z = (float4v){0.f, 0.f, 0.f, 0.f};
            short8 b0 = *(const short8*)&Ks[t * 16 + l16][q4 * 8];
            z = __builtin_amdgcn_mfma_f32_16x16x32_bf16(a0, b0, z, 0, 0, 0);
            short8 b1 = *(const short8*)&Ks[t * 16 + l16][32 + q4 * 8];
            s[t] = __builtin_amdgcn_mfma_f32_16x16x32_bf16(a1, b1, z, 0, 0, 0);
        }

        float m[4] = {-3e38f, -3e38f, -3e38f, -3e38f};
#pragma unroll
        for (int t = 0; t < 13; ++t)
#pragma unroll
            for (int i = 0; i < 4; ++i) {
                s[t][i] += bias_s[t * 16 + l16];
                m[i] = fmaxf(m[i], s[t][i]);
            }
#pragma unroll
        for (int o = 8; o > 0; o >>= 1)
#pragma unroll
            for (int i = 0; i < 4; ++i) m[i] = fmaxf(m[i], __shfl_xor(m[i], o));

        float ls[4] = {0.f, 0.f, 0.f, 0.f};
        float4v oacc[4];
#pragma unroll
        for (int tc = 0; tc < 4; ++tc) oacc[tc] = (float4v){0.f, 0.f, 0.f, 0.f};

#pragma unroll
        for (int cx = 0; cx < 4; ++cx) {
            const int ntt = (cx < 3) ? 4 : 1;
#pragma unroll
            for (int tt = 0; tt < 4; ++tt) {
                if (tt < ntt) {
                    int t = cx * 4 + tt;
#pragma unroll
                    for (int i = 0; i < 4; ++i) {
                        float p = __expf(s[t][i] - m[i]);
                        ls[i] += p;
                        Ps[wid][q4 * 4 + i][tt * 16 + l16] = f2bf(p);
                    }
                }
            }
            if (cx == 3) {
#pragma unroll
                for (int i = 0; i < 4; ++i)
                    Ps[wid][q4 * 4 + i][16 + l16] = 0;
            }
            const int nkk = (cx < 3) ? 2 : 1;
#pragma unroll
            for (int kx = 0; kx < 2; ++kx) {
                if (kx < nkk) {
                    short8 ap = *(const short8*)&Ps[wid][l16][kx * 32 + q4 * 8];
#pragma unroll
                    for (int tc = 0; tc < 4; ++tc) {
                        short8 vf = *(const short8*)
                            &Vt[tc * 16 + l16][(cx * 2 + kx) * 32 + q4 * 8];
                        oacc[tc] = __builtin_amdgcn_mfma_f32_16x16x32_bf16(
                            ap, vf, oacc[tc], 0, 0, 0);
                    }
                }
            }
        }

#pragma unroll
        for (int o = 8; o > 0; o >>= 1)
#pragma unroll
            for (int i = 0; i < 4; ++i) ls[i] += __shfl_xor(ls[i], o);

        float inv[4];
#pragma unroll
        for (int i = 0; i < 4; ++i) inv[i] = 1.0f / ls[i];
#pragma unroll
        for (int tc = 0; tc < 4; ++tc)
#pragma unroll
            for (int i = 0; i < 4; ++i) {
                int qrow = qt * 16 + q4 * 4 + i;
                if (qrow < PDIM) {
                    size_t dst = (rowb + 1 + fi * PDIM + qrow) * DIMM
                               + (size_t)hi * DH + tc * 16 + l16;
                    ab[dst] = f2bf(oacc[tc][i] * inv[i]);
                }
            }
    }
}

// ======================= launch =======================
extern "C" void kernel_launch(void* const* d_in, const int* in_sizes, int n_in,
                              void* d_out, int out_size, void* d_ws, size_t ws_size,
                              hipStream_t stream)
{
    const void* x     = d_in[0];
    const void* mask  = d_in[1];
    const void* Wqkv  = d_in[2];
    const void* Wproj = d_in[3];
    const void* bproj = d_in[4];
    float* out = (float*)d_out;

    int*    flags = (int*)d_ws;
    int*    cnt   = (int*)((char*)d_ws + 64);          // 192 finisher counters
    ushort* base  = (ushort*)((char*)d_ws + 4096);
    const size_t S = (size_t)MROWS * DIMM;
    ushort* qkv = base;                  // bf16 [M][2304] row-major
    ushort* ab  = qkv + 3 * S;           // attention out, bf16 [M][768]
    ushort* xb  = ab;                    // alias: xb dead before ab written
    ushort* wqkvT = ab + S;
    ushort* wprojT = wqkvT + (size_t)3 * DIMM * DIMM;
    float*  clsp   = (float*)(wprojT + (size_t)DIMM * DIMM);

    const int M    = MROWS;
    const int gM2  = (M + BM2 - 1) / BM2;   // 99

    // 0) prep: self-detect dtype + conv x->bf16 + transpose weights + zero cnt
    prep<<<CVB + TQB + TPB, 256, 0, stream>>>(
        x, xb, Wqkv, wqkvT, Wproj, wprojT, flags, cnt);

    // 1) qkv = x @ Wqkv — 256x256 8-phase (vmcnt(4)), bf16 out
    gemm256<0><<<gM2 * (3 * DIMM / BN2), 512, 0, stream>>>(
        xb, wqkvT, nullptr, qkv, nullptr, M, 3 * DIMM, DIMM, flags);

    // 2) fused attention: spatial [0,1536) + cls chunks [1536,3072)
    //    (last cls chunk per head combines via device-scope ticket)
    attn_all<<<NB * NH * FF + NB * NH * CCH, 512, 0, stream>>>(
        qkv, mask, ab, clsp, cnt, flags);

    // 3) out = ab @ Wproj + bias — 256x256 8-phase, fp32 out
    gemm256<1><<<gM2 * (DIMM / BN2), 512, 0, stream>>>(
        ab, wprojT, bproj, nullptr, out, M, DIMM, DIMM, flags);
}

// Round 13
// 420.659 us; speedup vs baseline: 1.1483x; 1.1483x over previous
//
#include <hip/hip_runtime.h>

// ---- problem constants (b=16, f=8, p=196, dim=768, H=12) ----
#define NB   16
#define NH   12
#define NSEQ 1569
#define DIMM 768
#define QS   (3 * DIMM)     // qkv row stride 2304
#define PDIM 196
#define FF   8
#define DH   64
#define MROWS (NB * NSEQ)   // 25104

typedef short short8 __attribute__((ext_vector_type(8)));
typedef float float4v __attribute__((ext_vector_type(4)));

__device__ __forceinline__ float bf2f(ushort u) {
    union { uint i; float f; } w; w.i = ((uint)u) << 16; return w.f;
}
__device__ __forceinline__ ushort f2bf(float f) {
    union { float f; uint i; } w; w.f = f;
    uint x = w.i;
    return (ushort)((x + 0x7FFFu + ((x >> 16) & 1u)) >> 16);
}
__device__ __forceinline__ float in_ld(const void* p, size_t idx, int f32) {
    return f32 ? ((const float*)p)[idx] : bf2f(((const ushort*)p)[idx]);
}

// async global->LDS, 16B per lane; LDS dest = wave-uniform base + lane*16
__device__ __forceinline__ void gload_lds16(const ushort* g, ushort* l) {
    __builtin_amdgcn_global_load_lds(
        (const __attribute__((address_space(1))) unsigned int*)g,
        (__attribute__((address_space(3))) unsigned int*)l,
        16, 0, 0);
}

// bijective XCD-aware block swizzle (m204)
__device__ __forceinline__ int xcd_swizzle(int orig, int nwg) {
    int qd = nwg >> 3, rd = nwg & 7;
    int xcd = orig & 7, loc = orig >> 3;
    return (xcd < rd ? xcd * (qd + 1) : rd * (qd + 1) + (xcd - rd) * qd) + loc;
}

// ======================= prep: self-detect + conv x->bf16 + transposes =======================
#define CVB 1024   // conv blocks
#define TQB 1728   // Wqkv transpose blocks (72 x 24)
#define TPB 576    // Wproj transpose blocks (24 x 24)

__device__ __forceinline__ void transpose_body(
    const void* __restrict__ W, ushort* __restrict__ WT,
    int K, int N, int b, int fl, ushort (*t)[33], int tid)
{
    const int nbx = N / 32;
    const int bx = b % nbx, by = b / nbx;
    const int tx = tid & 31, ty = tid >> 5;   // 32x8
#pragma unroll
    for (int i = 0; i < 4; ++i) {
        int r = by * 32 + ty + i * 8;
        t[ty + i * 8][tx] = f2bf(in_ld(W, (size_t)r * N + bx * 32 + tx, fl));
    }
    __syncthreads();
#pragma unroll
    for (int i = 0; i < 4; ++i) {
        int r = bx * 32 + ty + i * 8;
        WT[(size_t)r * K + by * 32 + tx] = t[tx][ty + i * 8];
    }
}

__global__ __launch_bounds__(256)
void prep(const void* __restrict__ x, ushort* __restrict__ xb,
          const void* __restrict__ Wqkv, ushort* __restrict__ wqkvT,
          const void* __restrict__ Wproj, ushort* __restrict__ wprojT,
          int* __restrict__ flags)
{
    __shared__ ushort t[32][33];
    __shared__ int anyBig;
    const int b = blockIdx.x, tid = threadIdx.x;

    // block-local dtype detect from Wqkv (fp32-as-ushort has random exponents)
    if (tid == 0) anyBig = 0;
    __syncthreads();
    {
        const ushort* w = (const ushort*)Wqkv;
        for (int i = tid; i < 2048; i += 256) {
            int e = (w[i] >> 7) & 0xFF;
            if (e >= 134) anyBig = 1;
        }
    }
    __syncthreads();
    const int fl = anyBig;

    if (b == 0 && tid == 0) flags[0] = fl;   // for downstream kernels

    if (b < CVB) {
        const size_t n = (size_t)MROWS * DIMM;
        const size_t stride = (size_t)CVB * 256;
        size_t i = (size_t)b * 256 + tid;
        if (fl) {
            for (size_t j = i; j < n / 4; j += stride) {
                float4 f = ((const float4*)x)[j];
                union { uint2 u; ushort s[4]; } w;
                w.s[0] = f2bf(f.x); w.s[1] = f2bf(f.y);
                w.s[2] = f2bf(f.z); w.s[3] = f2bf(f.w);
                ((uint2*)xb)[j] = w.u;
            }
        } else {
            for (size_t j = i; j < n / 8; j += stride)
                ((uint4*)xb)[j] = ((const uint4*)x)[j];
        }
    } else if (b < CVB + TQB) {
        transpose_body(Wqkv, wqkvT, DIMM, 3 * DIMM, b - CVB, fl, t, tid);
    } else {
        transpose_body(Wproj, wprojT, DIMM, DIMM, b - CVB - TQB, fl, t, tid);
    }
}

// ======================= 256x256 8-phase MFMA GEMM (R8 schedule) =======================
// A bf16 [M][K], Bt bf16 [N][K]. 8 waves (2Mx4N), per-wave out 128x64.
// LDS 128 KB: A/B x dbuf x 2 halves of [128][64].
// Schedule (4 phases per K-tile T, counted vmcnt, never 0):
//   B-frags of tile T are ds-read ONLY in T.p1 (held in regs), so B slot
//   frees after p1. Stage: A(T+1) at T.p1/p2; B(T+2) at T.p2/p3 into the
//   freed B half. At T.p4 boundary: outstanding = B(T+2) only = 4 gloads
//   -> s_waitcnt vmcnt(4); A(T+1)/B(T+1) (older) are forced complete.
// T2 swizzle (rule #21 both-sides): linear gload_lds dest; SOURCE slot
//   pre-XORed (sslot = (tid&7)^(row&7)); ds_read XORs slot with (row&7).
#define BM2 256
#define BN2 256
#define BK  64

#define STG_A(s, h, k0) do { \
    gload_lds16(aS[2*(h)]   + (k0), &As[s][h][(size_t)tid * 8]);        \
    gload_lds16(aS[2*(h)+1] + (k0), &As[s][h][(size_t)(tid + 512) * 8]); } while (0)
#define STG_B(s, h, k0) do { \
    gload_lds16(bS[2*(h)]   + (k0), &Bs[s][h][(size_t)tid * 8]);        \
    gload_lds16(bS[2*(h)+1] + (k0), &Bs[s][h][(size_t)(tid + 512) * 8]); } while (0)

#define PH_A_READS(m0) do { \
    af[0][0] = *(const short8*)(Acur + (m0) * 1024 + l16 * 64 + xs0);      \
    af[0][1] = *(const short8*)(Acur + (m0) * 1024 + l16 * 64 + xs1);      \
    af[1][0] = *(const short8*)(Acur + ((m0)+1) * 1024 + l16 * 64 + xs0);  \
    af[1][1] = *(const short8*)(Acur + ((m0)+1) * 1024 + l16 * 64 + xs1); } while (0)

#define PH_MFMA(m0) do { \
    asm volatile("" ::: "memory"); \
    __builtin_amdgcn_s_barrier(); \
    __builtin_amdgcn_s_setprio(1); \
    _Pragma("unroll") \
    for (int kk = 0; kk < 2; ++kk) \
        _Pragma("unroll") \
        for (int mi = 0; mi < 2; ++mi) \
            _Pragma("unroll") \
            for (int n = 0; n < 4; ++n) \
                acc[(m0)+mi][n] = __builtin_amdgcn_mfma_f32_16x16x32_bf16( \
                    af[mi][kk], bf[n][kk], acc[(m0)+mi][n], 0, 0, 0); \
    __builtin_amdgcn_s_setprio(0); } while (0)

#define PH_END() do { \
    asm volatile("" ::: "memory"); \
    __builtin_amdgcn_s_barrier(); } while (0)

#define PH_END_VM() do { \
    asm volatile("s_waitcnt vmcnt(4)" ::: "memory"); \
    __builtin_amdgcn_s_barrier(); } while (0)

template<int MODE>
__global__ __launch_bounds__(512, 2)
void gemm256(const ushort* __restrict__ A, const ushort* __restrict__ Bt,
             const void* __restrict__ bias,
             ushort* __restrict__ ob, float* __restrict__ of,
             int M, int N, int K, const int* __restrict__ flags)
{
    __shared__ __align__(16) ushort As[2][2][128 * 64];   // 64 KB
    __shared__ __align__(16) ushort Bs[2][2][128 * 64];   // 64 KB

    const int nbn = N / BN2;
    const int wg  = xcd_swizzle(blockIdx.x, gridDim.x);
    const int mb  = wg / nbn, nb = wg % nbn;
    const int Mb  = mb * BM2, Nbs = nb * BN2;

    const int tid = threadIdx.x, lane = tid & 63, wid = tid >> 6;
    const int wm  = wid >> 2;            // 0..1 : row half
    const int wn  = wid & 3;             // 0..3 : 64-col strip
    const int q4  = lane >> 4, l16 = lane & 15;

    // staging source (inverse-swizzled 16B slot)
    const int r0    = tid >> 3;                       // 0..63
    const int sslot = (tid & 7) ^ (r0 & 7);
    const ushort* aS[4]; const ushort* bS[4];
#pragma unroll
    for (int jj = 0; jj < 4; ++jj) {
        int ar = Mb + jj * 64 + r0; if (ar >= M) ar = M - 1;
        aS[jj] = A + (size_t)ar * K + sslot * 8;
        int br = Nbs + jj * 64 + r0;                  // N multiple of 256
        bS[jj] = Bt + (size_t)br * K + sslot * 8;
    }

    // ds_read swizzled slot offsets (row&7 == l16&7 since rows step by 16)
    const int xs0 = ((0 + q4) ^ (l16 & 7)) * 8;       // kk=0
    const int xs1 = ((4 + q4) ^ (l16 & 7)) * 8;       // kk=1

    float4v acc[8][4];
#pragma unroll
    for (int m = 0; m < 8; ++m)
#pragma unroll
        for (int n = 0; n < 4; ++n) acc[m][n] = (float4v){0.f, 0.f, 0.f, 0.f};

    const int NT = K / BK;   // 12

    // ---- prologue: A(0), B(0), B(1) ----
    STG_A(0, 0, 0); STG_A(0, 1, 0);
    STG_B(0, 0, 0); STG_B(0, 1, 0);
    STG_B(1, 0, BK); STG_B(1, 1, BK);
    asm volatile("s_waitcnt vmcnt(4)" ::: "memory");   // A(0),B(0) landed
    __builtin_amdgcn_s_barrier();

    for (int T = 0; T < NT; ++T) {
        const int cur = T & 1, nxt = cur ^ 1;
        const int k1 = (T + 1) * BK, k2 = (T + 2) * BK;
        const ushort* Acur = &As[cur][wm][0];
        short8 bf[4][2];
        short8 af[2][2];

        // ---- phase 1: read all B-frags + A rows 0-31; stage A0(T+1) ----
#pragma unroll
        for (int n = 0; n < 4; ++n) {
            int c = wn * 64 + n * 16 + l16;
            const ushort* Bh = &Bs[cur][c >> 7][(c & 127) * 64];
            bf[n][0] = *(const short8*)(Bh + xs0);
            bf[n][1] = *(const short8*)(Bh + xs1);
        }
        PH_A_READS(0);
        if (T + 1 < NT) STG_A(nxt, 0, k1);
        PH_MFMA(0);
        PH_END();

        // ---- phase 2: A rows 32-63; stage A1(T+1), B0(T+2) ----
        PH_A_READS(2);
        if (T + 1 < NT) STG_A(nxt, 1, k1);
        if (T + 2 < NT) STG_B(cur, 0, k2);
        PH_MFMA(2);
        PH_END();

        // ---- phase 3: A rows 64-95; stage B1(T+2) ----
        PH_A_READS(4);
        if (T + 2 < NT) STG_B(cur, 1, k2);
        PH_MFMA(4);
        PH_END();

        // ---- phase 4: A rows 96-127; boundary vmcnt(4) ----
        PH_A_READS(6);
        PH_MFMA(6);
        PH_END_VM();
    }

    // ---- epilogue ----
    const int fl = (MODE == 1) ? flags[0] : 0;
#pragma unroll
    for (int m = 0; m < 8; ++m)
#pragma unroll
        for (int n = 0; n < 4; ++n) {
            int col = Nbs + wn * 64 + n * 16 + l16;
            int rb  = Mb + wm * 128 + m * 16 + q4 * 4;
            if (MODE == 0) {
                float sc = (col < DIMM) ? 0.125f : 1.0f;
#pragma unroll
                for (int i = 0; i < 4; ++i) {
                    int row = rb + i;
                    if (row < M)
                        ob[(size_t)row * QS + col] = f2bf(acc[m][n][i] * sc);
                }
            } else {
                float bv = in_ld(bias, col, fl);
#pragma unroll
                for (int i = 0; i < 4; ++i) {
                    int row = rb + i;
                    if (row < M)
                        of[(size_t)row * N + col] = acc[m][n][i] + bv;
                }
            }
        }
}

// ======================= CLS attention — split-K partials =======================
#define CCH 8
#define CLK 197

__global__ __launch_bounds__(256)
void cls_attn_part(const ushort* __restrict__ qkv, const void* __restrict__ mask,
                   float* __restrict__ part, const int* __restrict__ flags)
{
    const int fl  = flags[0];
    const int bid = blockIdx.x;
    const int bh  = bid >> 3, ch = bid & 7;
    const int bi  = bh / NH, hi = bh - bi * NH;
    const int tid = threadIdx.x, lane = tid & 63, wid = tid >> 6;
    const int j0  = ch * CLK;
    const int j1  = (j0 + CLK < NSEQ) ? j0 + CLK : NSEQ;
    const int n   = j1 - j0;

    __shared__ float qs[DH];
    __shared__ float simbuf[CLK];
    __shared__ float redm[4], redl[4];
    __shared__ float osum[4][DH];

    const size_t rowb = (size_t)bi * NSEQ;
    if (tid < DH) qs[tid] = bf2f(qkv[rowb * QS + hi * DH + tid]);
    __syncthreads();

    for (int j = tid; j < n; j += 256) {
        int jj = j0 + j;
        const ushort* kr = qkv + (rowb + jj) * QS + DIMM + hi * DH;
        float s = 0.f;
#pragma unroll
        for (int c = 0; c < 8; ++c) {
            union { uint4 u; ushort e[8]; } w;
            w.u = *(const uint4*)(kr + c * 8);
#pragma unroll
            for (int i = 0; i < 8; ++i) s += qs[c * 8 + i] * bf2f(w.e[i]);
        }
        int sp = (jj == 0) ? 0 : 1 + ((jj - 1) % PDIM);
        s += (1.0f - in_ld(mask, bi * (1 + PDIM) + sp, fl)) * -10000.0f;
        simbuf[j] = s;
    }
    __syncthreads();

    float m = -3e38f;
    for (int j = tid; j < n; j += 256) m = fmaxf(m, simbuf[j]);
#pragma unroll
    for (int o = 32; o > 0; o >>= 1) m = fmaxf(m, __shfl_xor(m, o));
    if (lane == 0) redm[wid] = m;
    __syncthreads();
    m = fmaxf(fmaxf(redm[0], redm[1]), fmaxf(redm[2], redm[3]));

    float ls = 0.f;
    for (int j = tid; j < n; j += 256) {
        float p = __expf(simbuf[j] - m);
        simbuf[j] = p;
        ls += p;
    }
#pragma unroll
    for (int o = 32; o > 0; o >>= 1) ls += __shfl_xor(ls, o);
    if (lane == 0) redl[wid] = ls;
    __syncthreads();

    int g = wid, di = tid & 63;
    float acc = 0.f;
    for (int j = g; j < n; j += 4)
        acc += simbuf[j] * bf2f(qkv[(rowb + j0 + j) * QS + 2 * DIMM + hi * DH + di]);
    osum[g][di] = acc;
    __syncthreads();

    float* dst = part + (size_t)bid * (DH + 2);
    if (tid < DH)
        dst[2 + tid] = osum[0][tid] + osum[1][tid] + osum[2][tid] + osum[3][tid];
    if (tid == 0) { dst[0] = m; dst[1] = redl[0] + redl[1] + redl[2] + redl[3]; }
}

// ======================= spatial attention (+ cls combine appended) =======================
// blocks [0,1536): spatial (b,h,f); blocks [1536,1728): cls combine.
// __launch_bounds__(512, 4): 4 waves/EU = 16 waves/CU = 2 blocks/CU.
#define SQT   13
#define SKEY  208
#define KSTR  72
#define VSTR  232
#define PSC   72

__global__ __launch_bounds__(512, 4)
void spatial_attn_mfma(const ushort* __restrict__ qkv, const void* __restrict__ mask,
                       ushort* __restrict__ ab, const float* __restrict__ part,
                       const int* __restrict__ flags)
{
    const int fl  = flags[0];
    const int tid = threadIdx.x, lane = tid & 63, wid = tid >> 6;

    if (blockIdx.x >= 1536) {
        // ---- cls combine (192 blocks, 64 active lanes) ----
        if (tid >= DH) return;
        const int bh = blockIdx.x - 1536;
        const int d  = tid;
        const int bi = bh / NH, hi = bh - bi * NH;
        const float* p = part + (size_t)bh * CCH * (DH + 2);
        float m = -3e38f;
#pragma unroll
        for (int c = 0; c < CCH; ++c) m = fmaxf(m, p[c * (DH + 2)]);
        float l = 0.f, o = 0.f;
#pragma unroll
        for (int c = 0; c < CCH; ++c) {
            float w = __expf(p[c * (DH + 2)] - m);
            l += p[c * (DH + 2) + 1] * w;
            o += p[c * (DH + 2) + 2 + d] * w;
        }
        ab[((size_t)bi * NSEQ) * DIMM + hi * DH + d] = f2bf(o / l);
        return;
    }

    const int bhf = blockIdx.x;
    const int bh  = bhf >> 3, fi = bhf & 7;
    const int bi  = bh / NH, hi = bh - bi * NH;
    const int q4  = lane >> 4, l16 = lane & 15;

    __shared__ __align__(16) ushort Ks[SKEY][KSTR];   // 29.9 KB
    __shared__ __align__(16) ushort Vt[DH][VSTR];     // 29.0 KB
    __shared__ __align__(16) ushort Ps[8][16][PSC];   // 18.0 KB
    __shared__ float bias_s[SKEY];                    // ~77 KB total

    const size_t rowb = (size_t)bi * NSEQ;

    for (int j = tid; j < SKEY; j += 512)
        bias_s[j] = (j < 197) ? (1.0f - in_ld(mask, bi * 197 + j, fl)) * -10000.0f
                              : -3.0e38f;

    for (int c = tid; c < SKEY * (DH / 8); c += 512) {
        int j = c >> 3, off = (c & 7) * 8;
        int jj = j > 196 ? 196 : j;
        int row = (jj == 0) ? 0 : (fi * PDIM + jj);
        *(uint4*)&Ks[j][off] =
            *(const uint4*)(qkv + (rowb + row) * QS + DIMM + hi * DH + off);
    }
    for (int c = tid; c < 224 * (DH / 8); c += 512) {
        int j = c >> 3, off = (c & 7) * 8;
        int jj = j > 196 ? 196 : j;
        int row = (jj == 0) ? 0 : (fi * PDIM + jj);
        union { uint4 u; ushort e[8]; } w;
        w.u = *(const uint4*)(qkv + (rowb + row) * QS + 2 * DIMM + hi * DH + off);
#pragma unroll
        for (int i = 0; i < 8; ++i) Vt[off + i][j] = w.e[i];
    }
    __syncthreads();

    for (int qt = wid; qt < SQT; qt += 8) {
        int qi = qt * 16 + l16;
        int qc = qi > 195 ? 195 : qi;
        const ushort* qp = qkv + (rowb + 1 + fi * PDIM + qc) * QS + hi * DH;
        short8 a0 = *(const short8*)(qp + q4 * 8);
        short8 a1 = *(const short8*)(qp + 32 + q4 * 8);

        float4v s[13];
#pragma unroll
        for (int t = 0; t < 13; ++t) {
            float4v z = (float4v){0.f, 0.f, 0.f, 0.f};
            short8 b0 = *(const short8*)&Ks[t * 16 + l16][q4 * 8];
            z = __builtin_amdgcn_mfma_f32_16x16x32_bf16(a0, b0, z, 0, 0, 0);
            short8 b1 = *(const short8*)&Ks[t * 16 + l16][32 + q4 * 8];
            s[t] = __builtin_amdgcn_mfma_f32_16x16x32_bf16(a1, b1, z, 0, 0, 0);
        }

        float m[4] = {-3e38f, -3e38f, -3e38f, -3e38f};
#pragma unroll
        for (int t = 0; t < 13; ++t)
#pragma unroll
            for (int i = 0; i < 4; ++i) {
                s[t][i] += bias_s[t * 16 + l16];
                m[i] = fmaxf(m[i], s[t][i]);
            }
#pragma unroll
        for (int o = 8; o > 0; o >>= 1)
#pragma unroll
            for (int i = 0; i < 4; ++i) m[i] = fmaxf(m[i], __shfl_xor(m[i], o));

        float ls[4] = {0.f, 0.f, 0.f, 0.f};
        float4v oacc[4];
#pragma unroll
        for (int tc = 0; tc < 4; ++tc) oacc[tc] = (float4v){0.f, 0.f, 0.f, 0.f};

#pragma unroll
        for (int cx = 0; cx < 4; ++cx) {
            const int ntt = (cx < 3) ? 4 : 1;
#pragma unroll
            for (int tt = 0; tt < 4; ++tt) {
                if (tt < ntt) {
                    int t = cx * 4 + tt;
#pragma unroll
                    for (int i = 0; i < 4; ++i) {
                        float p = __expf(s[t][i] - m[i]);
                        ls[i] += p;
                        Ps[wid][q4 * 4 + i][tt * 16 + l16] = f2bf(p);
                    }
                }
            }
            if (cx == 3) {
#pragma unroll
                for (int i = 0; i < 4; ++i)
                    Ps[wid][q4 * 4 + i][16 + l16] = 0;
            }
            const int nkk = (cx < 3) ? 2 : 1;
#pragma unroll
            for (int kx = 0; kx < 2; ++kx) {
                if (kx < nkk) {
                    short8 ap = *(const short8*)&Ps[wid][l16][kx * 32 + q4 * 8];
#pragma unroll
                    for (int tc = 0; tc < 4; ++tc) {
                        short8 vf = *(const short8*)
                            &Vt[tc * 16 + l16][(cx * 2 + kx) * 32 + q4 * 8];
                        oacc[tc] = __builtin_amdgcn_mfma_f32_16x16x32_bf16(
                            ap, vf, oacc[tc], 0, 0, 0);
                    }
                }
            }
        }

#pragma unroll
        for (int o = 8; o > 0; o >>= 1)
#pragma unroll
            for (int i = 0; i < 4; ++i) ls[i] += __shfl_xor(ls[i], o);

        float inv[4];
#pragma unroll
        for (int i = 0; i < 4; ++i) inv[i] = 1.0f / ls[i];
#pragma unroll
        for (int tc = 0; tc < 4; ++tc)
#pragma unroll
            for (int i = 0; i < 4; ++i) {
                int qrow = qt * 16 + q4 * 4 + i;
                if (qrow < PDIM) {
                    size_t dst = (rowb + 1 + fi * PDIM + qrow) * DIMM
                               + (size_t)hi * DH + tc * 16 + l16;
                    ab[dst] = f2bf(oacc[tc][i] * inv[i]);
                }
            }
    }
}

// ======================= launch =======================
extern "C" void kernel_launch(void* const* d_in, const int* in_sizes, int n_in,
                              void* d_out, int out_size, void* d_ws, size_t ws_size,
                              hipStream_t stream)
{
    const void* x     = d_in[0];
    const void* mask  = d_in[1];
    const void* Wqkv  = d_in[2];
    const void* Wproj = d_in[3];
    const void* bproj = d_in[4];
    float* out = (float*)d_out;

    int*    flags = (int*)d_ws;
    ushort* base  = (ushort*)((char*)d_ws + 4096);
    const size_t S = (size_t)MROWS * DIMM;
    ushort* qkv = base;                  // bf16 [M][2304] row-major
    ushort* ab  = qkv + 3 * S;           // attention out, bf16 [M][768]
    ushort* xb  = ab;                    // alias: xb dead before ab written
    ushort* wqkvT = ab + S;
    ushort* wprojT = wqkvT + (size_t)3 * DIMM * DIMM;
    float*  clsp   = (float*)(wprojT + (size_t)DIMM * DIMM);

    const int M    = MROWS;
    const int gM2  = (M + BM2 - 1) / BM2;   // 99

    // 0) prep: self-detect dtype + conv x->bf16 + transpose weights
    prep<<<CVB + TQB + TPB, 256, 0, stream>>>(
        x, xb, Wqkv, wqkvT, Wproj, wprojT, flags);

    // 1) qkv = x @ Wqkv — 256x256 8-phase (vmcnt(4)), bf16 out
    gemm256<0><<<gM2 * (3 * DIMM / BN2), 512, 0, stream>>>(
        xb, wqkvT, nullptr, qkv, nullptr, M, 3 * DIMM, DIMM, flags);

    // 2) attention: cls partials, then spatial (+combine appended)
    cls_attn_part<<<NB * NH * CCH, 256, 0, stream>>>(qkv, mask, clsp, flags);
    spatial_attn_mfma<<<NB * NH * FF + NB * NH, 512, 0, stream>>>(
        qkv, mask, ab, clsp, flags);

    // 3) out = ab @ Wproj + bias — 256x256 8-phase, fp32 out
    gemm256<1><<<gM2 * (DIMM / BN2), 512, 0, stream>>>(
        ab, wprojT, bproj, nullptr, out, M, DIMM, DIMM, flags);
}

// Round 14
// 420.138 us; speedup vs baseline: 1.1498x; 1.0012x over previous
//
#include <hip/hip_runtime.h>

// ---- problem constants (b=16, f=8, p=196, dim=768, H=12) ----
#define NB   16
#define NH   12
#define NSEQ 1569
#define DIMM 768
#define QS   (3 * DIMM)     // qkv row stride 2304
#define PDIM 196
#define FF   8
#define DH   64
#define MROWS (NB * NSEQ)   // 25104

typedef short short8 __attribute__((ext_vector_type(8)));
typedef float float4v __attribute__((ext_vector_type(4)));

__device__ __forceinline__ float bf2f(ushort u) {
    union { uint i; float f; } w; w.i = ((uint)u) << 16; return w.f;
}
__device__ __forceinline__ ushort f2bf(float f) {
    union { float f; uint i; } w; w.f = f;
    uint x = w.i;
    return (ushort)((x + 0x7FFFu + ((x >> 16) & 1u)) >> 16);
}
__device__ __forceinline__ float in_ld(const void* p, size_t idx, int f32) {
    return f32 ? ((const float*)p)[idx] : bf2f(((const ushort*)p)[idx]);
}

// async global->LDS, 16B per lane; LDS dest = wave-uniform base + lane*16
__device__ __forceinline__ void gload_lds16(const ushort* g, ushort* l) {
    __builtin_amdgcn_global_load_lds(
        (const __attribute__((address_space(1))) unsigned int*)g,
        (__attribute__((address_space(3))) unsigned int*)l,
        16, 0, 0);
}

// bijective XCD-aware block swizzle (m204)
__device__ __forceinline__ int xcd_swizzle(int orig, int nwg) {
    int qd = nwg >> 3, rd = nwg & 7;
    int xcd = orig & 7, loc = orig >> 3;
    return (xcd < rd ? xcd * (qd + 1) : rd * (qd + 1) + (xcd - rd) * qd) + loc;
}

// ======================= transpose tile body (vectorized) =======================
// 32x32 tile, 256 threads = (c8 = tid&7 col-group of 4, r32 = tid>>3 row).
// t[32][36]: 72B row stride keeps 4-ushort (8B) stores aligned.
__device__ __forceinline__ void transpose_body(
    const void* __restrict__ W, ushort* __restrict__ WT,
    int K, int N, int b, int fl, ushort (*t)[36], int tid)
{
    const int nbx = N / 32;
    const int bx = b % nbx, by = b / nbx;
    const int c8 = tid & 7, r32 = tid >> 3;

    if (fl) {
        float4 f = *(const float4*)((const float*)W +
                                    (size_t)(by * 32 + r32) * N + bx * 32 + c8 * 4);
        union { uint2 u; ushort s[4]; } w;
        w.s[0] = f2bf(f.x); w.s[1] = f2bf(f.y);
        w.s[2] = f2bf(f.z); w.s[3] = f2bf(f.w);
        *(uint2*)&t[r32][c8 * 4] = w.u;
    } else {
        *(uint2*)&t[r32][c8 * 4] = *(const uint2*)((const ushort*)W +
                                    (size_t)(by * 32 + r32) * N + bx * 32 + c8 * 4);
    }
    __syncthreads();

    union { uint2 u; ushort s[4]; } o;
#pragma unroll
    for (int i = 0; i < 4; ++i) o.s[i] = t[c8 * 4 + i][r32];
    *(uint2*)(WT + (size_t)(bx * 32 + r32) * K + by * 32 + c8 * 4) = o.u;
}

// ======================= prep: self-detect + conv x->bf16 + Wqkv transpose =======================
#define CVB 1024   // conv blocks
#define TQB 1728   // Wqkv transpose blocks (72 x 24)
#define TPB 576    // Wproj transpose blocks (24 x 24) -- moved to cls launch

__global__ __launch_bounds__(256)
void prep(const void* __restrict__ x, ushort* __restrict__ xb,
          const void* __restrict__ Wqkv, ushort* __restrict__ wqkvT,
          int* __restrict__ flags)
{
    __shared__ ushort t[32][36];
    __shared__ int anyBig;
    const int b = blockIdx.x, tid = threadIdx.x;

    // block-local dtype detect from Wqkv (fp32-as-ushort has random exponents)
    if (tid == 0) anyBig = 0;
    __syncthreads();
    {
        const ushort* w = (const ushort*)Wqkv;
        for (int i = tid; i < 2048; i += 256) {
            int e = (w[i] >> 7) & 0xFF;
            if (e >= 134) anyBig = 1;
        }
    }
    __syncthreads();
    const int fl = anyBig;

    if (b == 0 && tid == 0) flags[0] = fl;   // for downstream kernels

    if (b < CVB) {
        const size_t n = (size_t)MROWS * DIMM;
        const size_t stride = (size_t)CVB * 256;
        size_t i = (size_t)b * 256 + tid;
        if (fl) {
            for (size_t j = i; j < n / 4; j += stride) {
                float4 f = ((const float4*)x)[j];
                union { uint2 u; ushort s[4]; } w;
                w.s[0] = f2bf(f.x); w.s[1] = f2bf(f.y);
                w.s[2] = f2bf(f.z); w.s[3] = f2bf(f.w);
                ((uint2*)xb)[j] = w.u;
            }
        } else {
            for (size_t j = i; j < n / 8; j += stride)
                ((uint4*)xb)[j] = ((const uint4*)x)[j];
        }
    } else {
        transpose_body(Wqkv, wqkvT, DIMM, 3 * DIMM, b - CVB, fl, t, tid);
    }
}

// ======================= 256x256 8-phase MFMA GEMM (R8 schedule) =======================
// A bf16 [M][K], Bt bf16 [N][K]. 8 waves (2Mx4N), per-wave out 128x64.
// LDS 128 KB: A/B x dbuf x 2 halves of [128][64].
// Schedule (4 phases per K-tile T, counted vmcnt, never 0):
//   B-frags of tile T are ds-read ONLY in T.p1 (held in regs), so B slot
//   frees after p1. Stage: A(T+1) at T.p1/p2; B(T+2) at T.p2/p3 into the
//   freed B half. At T.p4 boundary: outstanding = B(T+2) only = 4 gloads
//   -> s_waitcnt vmcnt(4); A(T+1)/B(T+1) (older) are forced complete.
// T2 swizzle (rule #21 both-sides): linear gload_lds dest; SOURCE slot
//   pre-XORed (sslot = (tid&7)^(row&7)); ds_read XORs slot with (row&7).
#define BM2 256
#define BN2 256
#define BK  64

#define STG_A(s, h, k0) do { \
    gload_lds16(aS[2*(h)]   + (k0), &As[s][h][(size_t)tid * 8]);        \
    gload_lds16(aS[2*(h)+1] + (k0), &As[s][h][(size_t)(tid + 512) * 8]); } while (0)
#define STG_B(s, h, k0) do { \
    gload_lds16(bS[2*(h)]   + (k0), &Bs[s][h][(size_t)tid * 8]);        \
    gload_lds16(bS[2*(h)+1] + (k0), &Bs[s][h][(size_t)(tid + 512) * 8]); } while (0)

#define PH_A_READS(m0) do { \
    af[0][0] = *(const short8*)(Acur + (m0) * 1024 + l16 * 64 + xs0);      \
    af[0][1] = *(const short8*)(Acur + (m0) * 1024 + l16 * 64 + xs1);      \
    af[1][0] = *(const short8*)(Acur + ((m0)+1) * 1024 + l16 * 64 + xs0);  \
    af[1][1] = *(const short8*)(Acur + ((m0)+1) * 1024 + l16 * 64 + xs1); } while (0)

#define PH_MFMA(m0) do { \
    asm volatile("" ::: "memory"); \
    __builtin_amdgcn_s_barrier(); \
    __builtin_amdgcn_s_setprio(1); \
    _Pragma("unroll") \
    for (int kk = 0; kk < 2; ++kk) \
        _Pragma("unroll") \
        for (int mi = 0; mi < 2; ++mi) \
            _Pragma("unroll") \
            for (int n = 0; n < 4; ++n) \
                acc[(m0)+mi][n] = __builtin_amdgcn_mfma_f32_16x16x32_bf16( \
                    af[mi][kk], bf[n][kk], acc[(m0)+mi][n], 0, 0, 0); \
    __builtin_amdgcn_s_setprio(0); } while (0)

#define PH_END() do { \
    asm volatile("" ::: "memory"); \
    __builtin_amdgcn_s_barrier(); } while (0)

#define PH_END_VM() do { \
    asm volatile("s_waitcnt vmcnt(4)" ::: "memory"); \
    __builtin_amdgcn_s_barrier(); } while (0)

template<int MODE>
__global__ __launch_bounds__(512, 2)
void gemm256(const ushort* __restrict__ A, const ushort* __restrict__ Bt,
             const void* __restrict__ bias,
             ushort* __restrict__ ob, float* __restrict__ of,
             int M, int N, int K, const int* __restrict__ flags)
{
    __shared__ __align__(16) ushort As[2][2][128 * 64];   // 64 KB
    __shared__ __align__(16) ushort Bs[2][2][128 * 64];   // 64 KB

    const int nbn = N / BN2;
    const int wg  = xcd_swizzle(blockIdx.x, gridDim.x);
    const int mb  = wg / nbn, nb = wg % nbn;
    const int Mb  = mb * BM2, Nbs = nb * BN2;

    const int tid = threadIdx.x, lane = tid & 63, wid = tid >> 6;
    const int wm  = wid >> 2;            // 0..1 : row half
    const int wn  = wid & 3;             // 0..3 : 64-col strip
    const int q4  = lane >> 4, l16 = lane & 15;

    // staging source (inverse-swizzled 16B slot)
    const int r0    = tid >> 3;                       // 0..63
    const int sslot = (tid & 7) ^ (r0 & 7);
    const ushort* aS[4]; const ushort* bS[4];
#pragma unroll
    for (int jj = 0; jj < 4; ++jj) {
        int ar = Mb + jj * 64 + r0; if (ar >= M) ar = M - 1;
        aS[jj] = A + (size_t)ar * K + sslot * 8;
        int br = Nbs + jj * 64 + r0;                  // N multiple of 256
        bS[jj] = Bt + (size_t)br * K + sslot * 8;
    }

    // ds_read swizzled slot offsets (row&7 == l16&7 since rows step by 16)
    const int xs0 = ((0 + q4) ^ (l16 & 7)) * 8;       // kk=0
    const int xs1 = ((4 + q4) ^ (l16 & 7)) * 8;       // kk=1

    float4v acc[8][4];
#pragma unroll
    for (int m = 0; m < 8; ++m)
#pragma unroll
        for (int n = 0; n < 4; ++n) acc[m][n] = (float4v){0.f, 0.f, 0.f, 0.f};

    const int NT = K / BK;   // 12

    // ---- prologue: A(0), B(0), B(1) ----
    STG_A(0, 0, 0); STG_A(0, 1, 0);
    STG_B(0, 0, 0); STG_B(0, 1, 0);
    STG_B(1, 0, BK); STG_B(1, 1, BK);
    asm volatile("s_waitcnt vmcnt(4)" ::: "memory");   // A(0),B(0) landed
    __builtin_amdgcn_s_barrier();

    for (int T = 0; T < NT; ++T) {
        const int cur = T & 1, nxt = cur ^ 1;
        const int k1 = (T + 1) * BK, k2 = (T + 2) * BK;
        const ushort* Acur = &As[cur][wm][0];
        short8 bf[4][2];
        short8 af[2][2];

        // ---- phase 1: read all B-frags + A rows 0-31; stage A0(T+1) ----
#pragma unroll
        for (int n = 0; n < 4; ++n) {
            int c = wn * 64 + n * 16 + l16;
            const ushort* Bh = &Bs[cur][c >> 7][(c & 127) * 64];
            bf[n][0] = *(const short8*)(Bh + xs0);
            bf[n][1] = *(const short8*)(Bh + xs1);
        }
        PH_A_READS(0);
        if (T + 1 < NT) STG_A(nxt, 0, k1);
        PH_MFMA(0);
        PH_END();

        // ---- phase 2: A rows 32-63; stage A1(T+1), B0(T+2) ----
        PH_A_READS(2);
        if (T + 1 < NT) STG_A(nxt, 1, k1);
        if (T + 2 < NT) STG_B(cur, 0, k2);
        PH_MFMA(2);
        PH_END();

        // ---- phase 3: A rows 64-95; stage B1(T+2) ----
        PH_A_READS(4);
        if (T + 2 < NT) STG_B(cur, 1, k2);
        PH_MFMA(4);
        PH_END();

        // ---- phase 4: A rows 96-127; boundary vmcnt(4) ----
        PH_A_READS(6);
        PH_MFMA(6);
        PH_END_VM();
    }

    // ---- epilogue ----
    const int fl = (MODE == 1) ? flags[0] : 0;
#pragma unroll
    for (int m = 0; m < 8; ++m)
#pragma unroll
        for (int n = 0; n < 4; ++n) {
            int col = Nbs + wn * 64 + n * 16 + l16;
            int rb  = Mb + wm * 128 + m * 16 + q4 * 4;
            if (MODE == 0) {
                float sc = (col < DIMM) ? 0.125f : 1.0f;
#pragma unroll
                for (int i = 0; i < 4; ++i) {
                    int row = rb + i;
                    if (row < M)
                        ob[(size_t)row * QS + col] = f2bf(acc[m][n][i] * sc);
                }
            } else {
                float bv = in_ld(bias, col, fl);
#pragma unroll
                for (int i = 0; i < 4; ++i) {
                    int row = rb + i;
                    if (row < M)
                        of[(size_t)row * N + col] = acc[m][n][i] + bv;
                }
            }
        }
}

// ======================= CLS attention — split-K partials (+ Wproj transpose) =======================
// blocks [0,1536): cls chunk (b,h,ch); blocks [1536,1536+TPB): Wproj transpose
// (wprojT needed only by the LAST launch -> safe to move off prep's critical path).
#define CCH 8
#define CLK 197

__global__ __launch_bounds__(256)
void cls_attn_part(const ushort* __restrict__ qkv, const void* __restrict__ mask,
                   float* __restrict__ part,
                   const void* __restrict__ Wproj, ushort* __restrict__ wprojT,
                   const int* __restrict__ flags)
{
    __shared__ ushort t[32][36];
    __shared__ float qs[DH];
    __shared__ float simbuf[CLK];
    __shared__ float redm[4], redl[4];
    __shared__ float osum[4][DH];

    const int fl  = flags[0];
    const int tid = threadIdx.x;

    if (blockIdx.x >= 1536) {
        transpose_body(Wproj, wprojT, DIMM, DIMM, blockIdx.x - 1536, fl, t, tid);
        return;
    }

    const int bid = blockIdx.x;
    const int bh  = bid >> 3, ch = bid & 7;
    const int bi  = bh / NH, hi = bh - bi * NH;
    const int lane = tid & 63, wid = tid >> 6;
    const int j0  = ch * CLK;
    const int j1  = (j0 + CLK < NSEQ) ? j0 + CLK : NSEQ;
    const int n   = j1 - j0;

    const size_t rowb = (size_t)bi * NSEQ;
    if (tid < DH) qs[tid] = bf2f(qkv[rowb * QS + hi * DH + tid]);
    __syncthreads();

    for (int j = tid; j < n; j += 256) {
        int jj = j0 + j;
        const ushort* kr = qkv + (rowb + jj) * QS + DIMM + hi * DH;
        float s = 0.f;
#pragma unroll
        for (int c = 0; c < 8; ++c) {
            union { uint4 u; ushort e[8]; } w;
            w.u = *(const uint4*)(kr + c * 8);
#pragma unroll
            for (int i = 0; i < 8; ++i) s += qs[c * 8 + i] * bf2f(w.e[i]);
        }
        int sp = (jj == 0) ? 0 : 1 + ((jj - 1) % PDIM);
        s += (1.0f - in_ld(mask, bi * (1 + PDIM) + sp, fl)) * -10000.0f;
        simbuf[j] = s;
    }
    __syncthreads();

    float m = -3e38f;
    for (int j = tid; j < n; j += 256) m = fmaxf(m, simbuf[j]);
#pragma unroll
    for (int o = 32; o > 0; o >>= 1) m = fmaxf(m, __shfl_xor(m, o));
    if (lane == 0) redm[wid] = m;
    __syncthreads();
    m = fmaxf(fmaxf(redm[0], redm[1]), fmaxf(redm[2], redm[3]));

    float ls = 0.f;
    for (int j = tid; j < n; j += 256) {
        float p = __expf(simbuf[j] - m);
        simbuf[j] = p;
        ls += p;
    }
#pragma unroll
    for (int o = 32; o > 0; o >>= 1) ls += __shfl_xor(ls, o);
    if (lane == 0) redl[wid] = ls;
    __syncthreads();

    int g = wid, di = tid & 63;
    float acc = 0.f;
    for (int j = g; j < n; j += 4)
        acc += simbuf[j] * bf2f(qkv[(rowb + j0 + j) * QS + 2 * DIMM + hi * DH + di]);
    osum[g][di] = acc;
    __syncthreads();

    float* dst = part + (size_t)bid * (DH + 2);
    if (tid < DH)
        dst[2 + tid] = osum[0][tid] + osum[1][tid] + osum[2][tid] + osum[3][tid];
    if (tid == 0) { dst[0] = m; dst[1] = redl[0] + redl[1] + redl[2] + redl[3]; }
}

// ======================= spatial attention (+ cls combine appended) =======================
// blocks [0,1536): spatial (b,h,f); blocks [1536,1728): cls combine.
// __launch_bounds__(512, 4): 4 waves/EU = 16 waves/CU = 2 blocks/CU.
#define SQT   13
#define SKEY  208
#define KSTR  72
#define VSTR  232
#define PSC   72

__global__ __launch_bounds__(512, 4)
void spatial_attn_mfma(const ushort* __restrict__ qkv, const void* __restrict__ mask,
                       ushort* __restrict__ ab, const float* __restrict__ part,
                       const int* __restrict__ flags)
{
    const int fl  = flags[0];
    const int tid = threadIdx.x, lane = tid & 63, wid = tid >> 6;

    if (blockIdx.x >= 1536) {
        // ---- cls combine (192 blocks, 64 active lanes) ----
        if (tid >= DH) return;
        const int bh = blockIdx.x - 1536;
        const int d  = tid;
        const int bi = bh / NH, hi = bh - bi * NH;
        const float* p = part + (size_t)bh * CCH * (DH + 2);
        float m = -3e38f;
#pragma unroll
        for (int c = 0; c < CCH; ++c) m = fmaxf(m, p[c * (DH + 2)]);
        float l = 0.f, o = 0.f;
#pragma unroll
        for (int c = 0; c < CCH; ++c) {
            float w = __expf(p[c * (DH + 2)] - m);
            l += p[c * (DH + 2) + 1] * w;
            o += p[c * (DH + 2) + 2 + d] * w;
        }
        ab[((size_t)bi * NSEQ) * DIMM + hi * DH + d] = f2bf(o / l);
        return;
    }

    const int bhf = blockIdx.x;
    const int bh  = bhf >> 3, fi = bhf & 7;
    const int bi  = bh / NH, hi = bh - bi * NH;
    const int q4  = lane >> 4, l16 = lane & 15;

    __shared__ __align__(16) ushort Ks[SKEY][KSTR];   // 29.9 KB
    __shared__ __align__(16) ushort Vt[DH][VSTR];     // 29.0 KB
    __shared__ __align__(16) ushort Ps[8][16][PSC];   // 18.0 KB
    __shared__ float bias_s[SKEY];                    // ~77 KB total

    const size_t rowb = (size_t)bi * NSEQ;

    for (int j = tid; j < SKEY; j += 512)
        bias_s[j] = (j < 197) ? (1.0f - in_ld(mask, bi * 197 + j, fl)) * -10000.0f
                              : -3.0e38f;

    for (int c = tid; c < SKEY * (DH / 8); c += 512) {
        int j = c >> 3, off = (c & 7) * 8;
        int jj = j > 196 ? 196 : j;
        int row = (jj == 0) ? 0 : (fi * PDIM + jj);
        *(uint4*)&Ks[j][off] =
            *(const uint4*)(qkv + (rowb + row) * QS + DIMM + hi * DH + off);
    }
    for (int c = tid; c < 224 * (DH / 8); c += 512) {
        int j = c >> 3, off = (c & 7) * 8;
        int jj = j > 196 ? 196 : j;
        int row = (jj == 0) ? 0 : (fi * PDIM + jj);
        union { uint4 u; ushort e[8]; } w;
        w.u = *(const uint4*)(qkv + (rowb + row) * QS + 2 * DIMM + hi * DH + off);
#pragma unroll
        for (int i = 0; i < 8; ++i) Vt[off + i][j] = w.e[i];
    }
    __syncthreads();

    for (int qt = wid; qt < SQT; qt += 8) {
        int qi = qt * 16 + l16;
        int qc = qi > 195 ? 195 : qi;
        const ushort* qp = qkv + (rowb + 1 + fi * PDIM + qc) * QS + hi * DH;
        short8 a0 = *(const short8*)(qp + q4 * 8);
        short8 a1 = *(const short8*)(qp + 32 + q4 * 8);

        float4v s[13];
#pragma unroll
        for (int t = 0; t < 13; ++t) {
            float4v z = (float4v){0.f, 0.f, 0.f, 0.f};
            short8 b0 = *(const short8*)&Ks[t * 16 + l16][q4 * 8];
            z = __builtin_amdgcn_mfma_f32_16x16x32_bf16(a0, b0, z, 0, 0, 0);
            short8 b1 = *(const short8*)&Ks[t * 16 + l16][32 + q4 * 8];
            s[t] = __builtin_amdgcn_mfma_f32_16x16x32_bf16(a1, b1, z, 0, 0, 0);
        }

        float m[4] = {-3e38f, -3e38f, -3e38f, -3e38f};
#pragma unroll
        for (int t = 0; t < 13; ++t)
#pragma unroll
            for (int i = 0; i < 4; ++i) {
                s[t][i] += bias_s[t * 16 + l16];
                m[i] = fmaxf(m[i], s[t][i]);
            }
#pragma unroll
        for (int o = 8; o > 0; o >>= 1)
#pragma unroll
            for (int i = 0; i < 4; ++i) m[i] = fmaxf(m[i], __shfl_xor(m[i], o));

        float ls[4] = {0.f, 0.f, 0.f, 0.f};
        float4v oacc[4];
#pragma unroll
        for (int tc = 0; tc < 4; ++tc) oacc[tc] = (float4v){0.f, 0.f, 0.f, 0.f};

#pragma unroll
        for (int cx = 0; cx < 4; ++cx) {
            const int ntt = (cx < 3) ? 4 : 1;
#pragma unroll
            for (int tt = 0; tt < 4; ++tt) {
                if (tt < ntt) {
                    int t = cx * 4 + tt;
#pragma unroll
                    for (int i = 0; i < 4; ++i) {
                        float p = __expf(s[t][i] - m[i]);
                        ls[i] += p;
                        Ps[wid][q4 * 4 + i][tt * 16 + l16] = f2bf(p);
                    }
                }
            }
            if (cx == 3) {
#pragma unroll
                for (int i = 0; i < 4; ++i)
                    Ps[wid][q4 * 4 + i][16 + l16] = 0;
            }
            const int nkk = (cx < 3) ? 2 : 1;
#pragma unroll
            for (int kx = 0; kx < 2; ++kx) {
                if (kx < nkk) {
                    short8 ap = *(const short8*)&Ps[wid][l16][kx * 32 + q4 * 8];
#pragma unroll
                    for (int tc = 0; tc < 4; ++tc) {
                        short8 vf = *(const short8*)
                            &Vt[tc * 16 + l16][(cx * 2 + kx) * 32 + q4 * 8];
                        oacc[tc] = __builtin_amdgcn_mfma_f32_16x16x32_bf16(
                            ap, vf, oacc[tc], 0, 0, 0);
                    }
                }
            }
        }

#pragma unroll
        for (int o = 8; o > 0; o >>= 1)
#pragma unroll
            for (int i = 0; i < 4; ++i) ls[i] += __shfl_xor(ls[i], o);

        float inv[4];
#pragma unroll
        for (int i = 0; i < 4; ++i) inv[i] = 1.0f / ls[i];
#pragma unroll
        for (int tc = 0; tc < 4; ++tc)
#pragma unroll
            for (int i = 0; i < 4; ++i) {
                int qrow = qt * 16 + q4 * 4 + i;
                if (qrow < PDIM) {
                    size_t dst = (rowb + 1 + fi * PDIM + qrow) * DIMM
                               + (size_t)hi * DH + tc * 16 + l16;
                    ab[dst] = f2bf(oacc[tc][i] * inv[i]);
                }
            }
    }
}

// ======================= launch =======================
extern "C" void kernel_launch(void* const* d_in, const int* in_sizes, int n_in,
                              void* d_out, int out_size, void* d_ws, size_t ws_size,
                              hipStream_t stream)
{
    const void* x     = d_in[0];
    const void* mask  = d_in[1];
    const void* Wqkv  = d_in[2];
    const void* Wproj = d_in[3];
    const void* bproj = d_in[4];
    float* out = (float*)d_out;

    int*    flags = (int*)d_ws;
    ushort* base  = (ushort*)((char*)d_ws + 4096);
    const size_t S = (size_t)MROWS * DIMM;
    ushort* qkv = base;                  // bf16 [M][2304] row-major
    ushort* ab  = qkv + 3 * S;           // attention out, bf16 [M][768]
    ushort* xb  = ab;                    // alias: xb dead before ab written
    ushort* wqkvT = ab + S;
    ushort* wprojT = wqkvT + (size_t)3 * DIMM * DIMM;
    float*  clsp   = (float*)(wprojT + (size_t)DIMM * DIMM);

    const int M    = MROWS;
    const int gM2  = (M + BM2 - 1) / BM2;   // 99

    // 0) prep: self-detect dtype + conv x->bf16 + Wqkv transpose
    prep<<<CVB + TQB, 256, 0, stream>>>(x, xb, Wqkv, wqkvT, flags);

    // 1) qkv = x @ Wqkv — 256x256 8-phase (vmcnt(4)), bf16 out
    gemm256<0><<<gM2 * (3 * DIMM / BN2), 512, 0, stream>>>(
        xb, wqkvT, nullptr, qkv, nullptr, M, 3 * DIMM, DIMM, flags);

    // 2) attention: cls partials (+Wproj transpose), then spatial (+combine)
    cls_attn_part<<<NB * NH * CCH + TPB, 256, 0, stream>>>(
        qkv, mask, clsp, Wproj, wprojT, flags);
    spatial_attn_mfma<<<NB * NH * FF + NB * NH, 512, 0, stream>>>(
        qkv, mask, ab, clsp, flags);

    // 3) out = ab @ Wproj + bias — 256x256 8-phase, fp32 out
    gemm256<1><<<gM2 * (DIMM / BN2), 512, 0, stream>>>(
        ab, wprojT, bproj, nullptr, out, M, DIMM, DIMM, flags);
}